// Round 2
// baseline (135.840 us; speedup 1.0000x reference)
//
#include <hip/hip_runtime.h>
#include <hip/hip_bf16.h>
#include <math.h>

// B=16, H=64, W=64, C=64 -> N=4096 pixels/batch, M=1024 pooled cells.
#define NB 16
#define NPIX 4096
#define MPOOL 1024

typedef __attribute__((ext_vector_type(8))) short bf16x8;  // 8 bf16 (4 VGPRs)
typedef __attribute__((ext_vector_type(4))) float f32x4;   // MFMA C/D frag

__device__ inline unsigned short f2bf(float f) {
    __hip_bfloat16 h = __float2bfloat16(f);
    return *reinterpret_cast<unsigned short*>(&h);
}

// Packed f32x2 -> bf16x2 in one dword: low 16 = bf16(a), high 16 = bf16(b).
#if defined(__has_builtin)
#if __has_builtin(__builtin_amdgcn_cvt_pk_bf16_f32)
#define HAVE_PK_BF16 1
#endif
#endif
__device__ inline unsigned pack_bf16(float a, float b) {
#ifdef HAVE_PK_BF16
    typedef __bf16 bf16v2 __attribute__((ext_vector_type(2)));
    bf16v2 v = __builtin_amdgcn_cvt_pk_bf16_f32(a, b);
    unsigned u;
    __builtin_memcpy(&u, &v, 4);
    return u;
#else
    unsigned ua = __float_as_uint(a) + 0x8000u;
    unsigned ub = __float_as_uint(b) + 0x8000u;
    return __builtin_amdgcn_perm(ua, ub, 0x03020706u);
#endif
}

// Workspace layout (u16 elements from start of ws):
//   theta_bf @0       [16*4096*8]
//   phi_bf   @524288  [16*1024*8]
//   gT_bf    @655360  [16*32*1024]

__device__ inline float wave_sum64(float v) {
    #pragma unroll
    for (int off = 32; off >= 1; off >>= 1) v += __shfl_xor(v, off);
    return v;
}

// Wave-local spectral norm (one power-iteration step, matches reference).
// Whole wave must enter. Returns 1/sigma (wave-uniform). No LDS, no barriers:
// cross-lane via shuffles only (shuffles hoisted out of divergent guards).
template<int D, int COUT>
__device__ float sn_inv_sigma(const float* __restrict__ w, const float* __restrict__ u) {
    const int lane = threadIdx.x & 63;
    float vi = 0.f;
    if (lane < D) {
        #pragma unroll 8
        for (int j = 0; j < COUT; ++j) vi += w[lane * COUT + j] * u[j];
    }
    float nn = wave_sum64(vi * vi);
    vi *= 1.0f / (sqrtf(nn) + 1e-12f);

    float u2 = 0.f;
    #pragma unroll 8
    for (int i = 0; i < D; ++i) {
        float vv = __shfl(vi, i);                   // all lanes execute the shuffle
        if (lane < COUT) u2 += w[i * COUT + lane] * vv;
    }
    float nn2 = wave_sum64(u2 * u2);
    u2 *= 1.0f / (sqrtf(nn2) + 1e-12f);

    float ti = 0.f;
    #pragma unroll 8
    for (int j = 0; j < COUT; ++j) {
        float uv = __shfl(u2, j);
        if (lane < D) ti += w[lane * COUT + j] * uv;
    }
    float sig = wave_sum64(vi * ti);
    return 1.0f / sig;
}

// ---------------- fused SN + conv: theta + (phi,g)+maxpool via MFMA ----------------
// Block = 256 thr = 4 waves; covers one 2-row pixel strip (128 px) of one image.
// SN computed redundantly per block (waves 0-2), weights L2-hot.
__global__ __launch_bounds__(256) void conv_all_kernel(const float* __restrict__ x,
                                                       const float* __restrict__ w_theta, const float* __restrict__ u_theta,
                                                       const float* __restrict__ w_phi,   const float* __restrict__ u_phi,
                                                       const float* __restrict__ w_g,     const float* __restrict__ u_g,
                                                       unsigned short* __restrict__ theta_bf,
                                                       unsigned short* __restrict__ phi_bf,
                                                       unsigned short* __restrict__ gT_bf) {
    __shared__ unsigned short sx[128 * 72];  // x strip bf16, row pad 72 (reused for out-staging)
    __shared__ unsigned short sw[48 * 72];   // W^T [col][k], pad 72
    __shared__ float s_inv[3];

    const int tid  = threadIdx.x;
    const int b    = blockIdx.x >> 5;
    const int hp   = blockIdx.x & 31;        // rows 2hp, 2hp+1
    const int h0   = hp * 2;
    const int wv   = tid >> 6;
    const int lane = tid & 63;
    const int quad = lane >> 4;
    const int lcol = lane & 15;
    const int w0   = wv * 16;

    // stage x strip: 8192 floats = 2048 float4 -> 8 iters
    const float4* xb4 = (const float4*)(x + (((size_t)b * NPIX) + h0 * 64) * 64);
    #pragma unroll
    for (int it = 0; it < 8; ++it) {
        const int li = tid + it * 256;
        float4 v = xb4[li];
        const int px = li >> 4, c4 = li & 15;
        uint2 pk;
        pk.x = pack_bf16(v.x, v.y);
        pk.y = pack_bf16(v.z, v.w);
        *(uint2*)(&sx[px * 72 + c4 * 4]) = pk;
    }
    // per-wave spectral norm (redundant across blocks; weights are tiny + L2-hot)
    if (wv == 0)      { float iv = sn_inv_sigma<64, 8>(w_theta, u_theta); if (lane == 0) s_inv[0] = iv; }
    else if (wv == 1) { float iv = sn_inv_sigma<64, 8>(w_phi,   u_phi);   if (lane == 0) s_inv[1] = iv; }
    else if (wv == 2) { float iv = sn_inv_sigma<64, 32>(w_g,    u_g);     if (lane == 0) s_inv[2] = iv; }
    __syncthreads();

    // fill sw: cols 0-7 theta, 8-15 phi, 16-47 g; sw[col][k] = bf16(w[k][col]/sigma)
    {
        const float i0 = s_inv[0], i1 = s_inv[1], i2 = s_inv[2];
        #pragma unroll
        for (int it = 0; it < 12; ++it) {
            const int idx = tid + it * 256;      // 0..3071; col is wave-uniform per iter
            const int col = idx >> 6, k = idx & 63;
            float wvf, inv;
            if (col < 8)       { wvf = w_theta[k * 8 + col];        inv = i0; }
            else if (col < 16) { wvf = w_phi[k * 8 + (col - 8)];    inv = i1; }
            else               { wvf = w_g[k * 32 + (col - 16)];    inv = i2; }
            sw[col * 72 + k] = f2bf(wvf * inv);
        }
    }
    __syncthreads();

    bf16x8 a[2][2];
    #pragma unroll
    for (int hh = 0; hh < 2; ++hh)
        #pragma unroll
        for (int kc = 0; kc < 2; ++kc)
            a[hh][kc] = *(const bf16x8*)(sx + (hh * 64 + w0 + lcol) * 72 + kc * 32 + quad * 8);

    f32x4 acc[2][3];
    #pragma unroll
    for (int ct = 0; ct < 3; ++ct) {
        bf16x8 b0 = *(const bf16x8*)(sw + (ct * 16 + lcol) * 72 + 0 * 32 + quad * 8);
        bf16x8 b1 = *(const bf16x8*)(sw + (ct * 16 + lcol) * 72 + 1 * 32 + quad * 8);
        #pragma unroll
        for (int hh = 0; hh < 2; ++hh) {
            f32x4 c = __builtin_amdgcn_mfma_f32_16x16x32_bf16(a[hh][0], b0, (f32x4)0.0f, 0, 0, 0);
            acc[hh][ct] = __builtin_amdgcn_mfma_f32_16x16x32_bf16(a[hh][1], b1, c, 0, 0, 0);
        }
    }
    __syncthreads();   // all LDS reads of sx/sw done -> safe to overlay staging tiles

    // ---- stage outputs in LDS (overlaid on sx), then write coalesced ----
    // th: 128px x 8ch = 1024 u16 @sx+0 ; ph: 32m x 8ch = 256 u16 @sx+1024 ;
    // gg: 32ch x 32m = 1024 u16 @sx+1280
    unsigned short* th = sx;
    unsigned short* ph = sx + 1024;
    unsigned short* gg = sx + 1280;
    const int ml = (w0 >> 1) + quad * 2;     // local pooled m within block, 0..31
    if (lcol < 8) {
        #pragma unroll
        for (int hh = 0; hh < 2; ++hh) {
            const int pix = hh * 64 + w0 + quad * 4;
            #pragma unroll
            for (int r = 0; r < 4; ++r)
                th[(pix + r) * 8 + lcol] = f2bf(acc[hh][0][r]);
        }
    } else {
        #pragma unroll
        for (int r2 = 0; r2 < 2; ++r2) {
            float pe = fmaxf(fmaxf(acc[0][0][2 * r2], acc[0][0][2 * r2 + 1]),
                             fmaxf(acc[1][0][2 * r2], acc[1][0][2 * r2 + 1]));
            ph[(ml + r2) * 8 + (lcol - 8)] = f2bf(pe);
        }
    }
    #pragma unroll
    for (int ct = 1; ct < 3; ++ct) {
        const int cg = (ct - 1) * 16 + lcol;
        #pragma unroll
        for (int r2 = 0; r2 < 2; ++r2) {
            float pe = fmaxf(fmaxf(acc[0][ct][2 * r2], acc[0][ct][2 * r2 + 1]),
                             fmaxf(acc[1][ct][2 * r2], acc[1][ct][2 * r2 + 1]));
            gg[cg * 32 + ml + r2] = f2bf(pe);
        }
    }
    __syncthreads();

    // coalesced global writes: 288 float4 total (th 128, ph 32, gg 128)
    const float4* sv4 = (const float4*)sx;
    float4* th4 = (float4*)(theta_bf + ((size_t)b * NPIX + hp * 128) * 8);
    float4* ph4 = (float4*)(phi_bf + ((size_t)b * MPOOL + hp * 32) * 8);
    for (int idx = tid; idx < 288; idx += 256) {
        float4 v = sv4[idx];
        if (idx < 128) {
            th4[idx] = v;
        } else if (idx < 160) {
            ph4[idx - 128] = v;
        } else {
            const int gi = idx - 160;            // 0..127
            const int ch = gi >> 2, part = gi & 3;
            *(float4*)(gT_bf + ((size_t)b * 32 + ch) * MPOOL + hp * 32 + part * 8) = v;
        }
    }
}

// ---------------- fused SN(w_o) + MFMA attention + output conv + residual ----------------
// Block = 512 thr = 8 waves; wave = 16 q rows. Grid = 16 b x 32 qb.
// Single pass (no max subtraction: scores ~N(0,2), max ~11 << 88, fp32 exp safe).
// QK computed TRANSPOSED (A=phi, B=theta): lane's C-regs = 4 consecutive m's for
// fixed q=lcol -> uint2 P stores, per-lane ls.
// Epilogue: out-conv with A=wo, B=ag -> D[ch][q], float4 residual stores;
// softmax 1/ls folded post-conv (per-q scaling commutes with channel conv).
__global__ __launch_bounds__(512) void attn_kernel(const unsigned short* __restrict__ theta_bf,
                                                   const unsigned short* __restrict__ phi_bf,
                                                   const unsigned short* __restrict__ gT_bf,
                                                   const float* __restrict__ w_o,
                                                   const float* __restrict__ u_o,
                                                   const float* __restrict__ x,
                                                   const float* __restrict__ gamma,
                                                   float* __restrict__ out) {
    __shared__ unsigned short sphi[MPOOL * 8];   // 16 KB
    __shared__ unsigned short sg[2][32 * 264];   // 33.8 KB: gT tile [32 ch][256 m + 8 pad]
    __shared__ unsigned short sP[8][16 * 72];    // 18.4 KB: per-wave P 16q x 64m, stride 72
    __shared__ unsigned short swo[64 * 40];      // 5.1 KB: woT [64 co][32 k + 8 pad]

    const int tid  = threadIdx.x;
    const int b    = blockIdx.x >> 5;
    const int qb   = blockIdx.x & 31;
    const int w    = tid >> 6;
    const int lane = tid & 63;
    const int quad = lane >> 4;
    const int lcol = lane & 15;

    // stage phi[b] (16 KB)
    {
        const float4* src = (const float4*)(phi_bf + (size_t)b * (MPOOL * 8));
        float4* dst = (float4*)sphi;
        dst[2 * tid]     = src[2 * tid];
        dst[2 * tid + 1] = src[2 * tid + 1];
    }
    // stage gT tile 0
    const unsigned short* gTb = gT_bf + (size_t)b * (32 * MPOOL);
    const int prow = tid >> 4, pseg = tid & 15;
    {
        const float4* src = (const float4*)(gTb + prow * MPOOL + pseg * 16);
        float4 r0 = src[0], r1 = src[1];
        float4* dst = (float4*)(&sg[0][prow * 264 + pseg * 16]);
        dst[0] = r0; dst[1] = r1;
    }
    // theta frag (K=8 real, zero-pad k>=8 -> quads 1-3 zero); used as B operand.
    const int q0w = qb * 128 + w * 16;
    bf16x8 tfrag = (bf16x8)(short)0;
    if (quad == 0)
        tfrag = *(const bf16x8*)(theta_bf + ((size_t)b * NPIX + q0w + lcol) * 8);
    // SN for w_o (d=32, cout=64): every wave computes it redundantly (no cross-wave
    // broadcast needed; w_o is 8 KB and L2-hot). ~matvec-chain latency, overlaps staging.
    const float wo_inv = sn_inv_sigma<32, 64>(w_o, u_o);
    __syncthreads();

    // fill swo[n*40+k] = bf16(w_o[k*64+n]/sigma); consumed only in the epilogue
    // (t-loop barriers cover visibility).
    for (int idx = tid; idx < 64 * 32; idx += 512) {
        const int n = idx >> 5, k = idx & 31;
        swo[n * 40 + k] = f2bf(w_o[k * 64 + n] * wo_inv);
    }

    f32x4 olo = (f32x4)0.0f, ohi = (f32x4)0.0f;
    float ls = 0.f;
    unsigned short* sPw = sP[w];

    float4 pre0, pre1;
    for (int t = 0; t < 4; ++t) {
        if (t < 3) {
            const float4* src = (const float4*)(gTb + prow * MPOOL + (t + 1) * 256 + pseg * 16);
            pre0 = src[0]; pre1 = src[1];
        }
        const unsigned short* sgb = sg[t & 1];
        for (int cb = 0; cb < 4; ++cb) {
            const int m0 = t * 256 + cb * 64;
            f32x4 s[4];
            #pragma unroll
            for (int sc = 0; sc < 4; ++sc) {
                bf16x8 pf = *(const bf16x8*)(sphi + (size_t)(m0 + sc * 16 + lcol) * 8);
                // S^T tile: D[row=m (quad*4+r within sc*16)][col=q (lcol)]
                s[sc] = __builtin_amdgcn_mfma_f32_16x16x32_bf16(pf, tfrag, (f32x4)0.0f, 0, 0, 0);
            }
            #pragma unroll
            for (int sc = 0; sc < 4; ++sc) {
                float e0 = __expf(s[sc][0]);
                float e1 = __expf(s[sc][1]);
                float e2 = __expf(s[sc][2]);
                float e3 = __expf(s[sc][3]);
                ls += (e0 + e1) + (e2 + e3);
                uint2 pk2;
                pk2.x = (unsigned)f2bf(e0) | ((unsigned)f2bf(e1) << 16);
                pk2.y = (unsigned)f2bf(e2) | ((unsigned)f2bf(e3) << 16);
                // P[q=lcol][m-in-chunk = sc*16 + quad*4 .. +3]
                *(uint2*)(sPw + lcol * 72 + sc * 16 + quad * 4) = pk2;
            }
            asm volatile("s_waitcnt lgkmcnt(0)" ::: "memory");
            #pragma unroll
            for (int pkk = 0; pkk < 2; ++pkk) {
                bf16x8 afrag = *(const bf16x8*)(sPw + lcol * 72 + pkk * 32 + quad * 8);
                bf16x8 bg0 = *(const bf16x8*)(sgb + lcol * 264 + cb * 64 + pkk * 32 + quad * 8);
                olo = __builtin_amdgcn_mfma_f32_16x16x32_bf16(afrag, bg0, olo, 0, 0, 0);
                bf16x8 bg1 = *(const bf16x8*)(sgb + (16 + lcol) * 264 + cb * 64 + pkk * 32 + quad * 8);
                ohi = __builtin_amdgcn_mfma_f32_16x16x32_bf16(afrag, bg1, ohi, 0, 0, 0);
            }
        }
        if (t < 3) {
            float4* dst = (float4*)(&sg[(t + 1) & 1][prow * 264 + pseg * 16]);
            dst[0] = pre0; dst[1] = pre1;
        }
        __syncthreads();
    }

    // total softmax denominator for q = lcol: sum over quads (lanes lcol+16k)
    ls += __shfl_xor(ls, 16);
    ls += __shfl_xor(ls, 32);
    const float invq = 1.0f / ls;

    // ag (UNNORMALIZED) -> per-wave LDS round-trip: [q][ch], stride 40
    #pragma unroll
    for (int r = 0; r < 4; ++r) {
        sPw[(quad * 4 + r) * 40 + lcol]      = f2bf(olo[r]);
        sPw[(quad * 4 + r) * 40 + 16 + lcol] = f2bf(ohi[r]);
    }
    asm volatile("s_waitcnt lgkmcnt(0)" ::: "memory");
    bf16x8 agf = *(const bf16x8*)(sPw + lcol * 40 + quad * 8);  // B[k=ch][n=q=lcol]

    const float gmi = gamma[0] * invq;
    const size_t pixbase = ((size_t)b * NPIX + q0w + lcol) * 64;
    #pragma unroll
    for (int ct = 0; ct < 4; ++ct) {
        bf16x8 wa = *(const bf16x8*)(swo + (ct * 16 + lcol) * 40 + quad * 8);  // A[co][k]
        f32x4 oc = __builtin_amdgcn_mfma_f32_16x16x32_bf16(wa, agf, (f32x4)0.0f, 0, 0, 0);
        // oc[r] = channel ct*16 + quad*4 + r at pixel q0w + lcol
        const float4 xv = *(const float4*)(x + pixbase + ct * 16 + quad * 4);
        float4 ov;
        ov.x = xv.x + gmi * oc[0];
        ov.y = xv.y + gmi * oc[1];
        ov.z = xv.z + gmi * oc[2];
        ov.w = xv.w + gmi * oc[3];
        *(float4*)(out + pixbase + ct * 16 + quad * 4) = ov;
    }
}

extern "C" void kernel_launch(void* const* d_in, const int* in_sizes, int n_in,
                              void* d_out, int out_size, void* d_ws, size_t ws_size,
                              hipStream_t stream) {
    const float* x       = (const float*)d_in[0];
    const float* w_theta = (const float*)d_in[1];
    const float* u_theta = (const float*)d_in[2];
    const float* w_phi   = (const float*)d_in[3];
    const float* u_phi   = (const float*)d_in[4];
    const float* w_g     = (const float*)d_in[5];
    const float* u_g     = (const float*)d_in[6];
    const float* w_o     = (const float*)d_in[7];
    const float* u_o     = (const float*)d_in[8];
    const float* gamma   = (const float*)d_in[9];
    float* out = (float*)d_out;

    unsigned short* u16base  = (unsigned short*)d_ws;
    unsigned short* theta_bf = u16base;                  // 524288
    unsigned short* phi_bf   = u16base + 524288;         // 131072
    unsigned short* gT_bf    = u16base + 655360;         // 524288

    conv_all_kernel<<<512, 256, 0, stream>>>(x, w_theta, u_theta, w_phi, u_phi, w_g, u_g,
                                             theta_bf, phi_bf, gT_bf);
    attn_kernel<<<512, 512, 0, stream>>>(theta_bf, phi_bf, gT_bf, w_o, u_o, x, gamma, out);
}

// Round 3
// 120.445 us; speedup vs baseline: 1.1278x; 1.1278x over previous
//
#include <hip/hip_runtime.h>
#include <hip/hip_bf16.h>
#include <math.h>

// B=16, H=64, W=64, C=64 -> N=4096 pixels/batch, M=1024 pooled cells.
#define NB 16
#define NPIX 4096
#define MPOOL 1024

typedef __attribute__((ext_vector_type(8))) short bf16x8;  // 8 bf16 (4 VGPRs)
typedef __attribute__((ext_vector_type(4))) float f32x4;   // MFMA C/D frag

#define LOG2E 1.44269504088896340736f

__device__ inline unsigned short f2bf(float f) {
    __hip_bfloat16 h = __float2bfloat16(f);
    return *reinterpret_cast<unsigned short*>(&h);
}

// Packed f32x2 -> bf16x2 in one dword: low 16 = bf16(a), high 16 = bf16(b).
#if defined(__has_builtin)
#if __has_builtin(__builtin_amdgcn_cvt_pk_bf16_f32)
#define HAVE_PK_BF16 1
#endif
#endif
__device__ inline unsigned pack_bf16(float a, float b) {
#ifdef HAVE_PK_BF16
    typedef __bf16 bf16v2 __attribute__((ext_vector_type(2)));
    bf16v2 v = __builtin_amdgcn_cvt_pk_bf16_f32(a, b);
    unsigned u;
    __builtin_memcpy(&u, &v, 4);
    return u;
#else
    unsigned ua = __float_as_uint(a) + 0x8000u;
    unsigned ub = __float_as_uint(b) + 0x8000u;
    return __builtin_amdgcn_perm(ua, ub, 0x03020706u);
#endif
}

// Workspace layout (u16 elements from start of ws):
//   theta_bf @0        [16*4096*8]   (PRE-SCALED by log2e for exp2-softmax)
//   phi_bf   @524288   [16*1024*8]
//   gT_bf    @655360   [16*32*1024]
//   woT_bf   @1179648  [64*32]       (SN'd w_o, transposed [co][k])

__device__ inline float wave_sum64(float v) {
    #pragma unroll
    for (int off = 32; off >= 1; off >>= 1) v += __shfl_xor(v, off);
    return v;
}

// Wave-local spectral norm (one power-iteration step, matches reference).
// Whole wave must enter. Returns 1/sigma (wave-uniform).
template<int D, int COUT>
__device__ float sn_inv_sigma(const float* __restrict__ w, const float* __restrict__ u) {
    const int lane = threadIdx.x & 63;
    float vi = 0.f;
    if (lane < D) {
        #pragma unroll 8
        for (int j = 0; j < COUT; ++j) vi += w[lane * COUT + j] * u[j];
    }
    float nn = wave_sum64(vi * vi);
    vi *= 1.0f / (sqrtf(nn) + 1e-12f);

    float u2 = 0.f;
    #pragma unroll 8
    for (int i = 0; i < D; ++i) {
        float vv = __shfl(vi, i);                   // all lanes execute the shuffle
        if (lane < COUT) u2 += w[i * COUT + lane] * vv;
    }
    float nn2 = wave_sum64(u2 * u2);
    u2 *= 1.0f / (sqrtf(nn2) + 1e-12f);

    float ti = 0.f;
    #pragma unroll 8
    for (int j = 0; j < COUT; ++j) {
        float uv = __shfl(u2, j);
        if (lane < D) ti += w[lane * COUT + j] * uv;
    }
    float sig = wave_sum64(vi * ti);
    return 1.0f / sig;
}

// ---------------- fused SN + conv: theta + (phi,g)+maxpool via MFMA ----------------
// Block = 256 thr = 4 waves; covers one 2-row pixel strip (128 px) of one image.
// SN computed per block: waves 0-2 do theta/phi/g; block 0's wave 3 does w_o -> woT_bf.
__global__ __launch_bounds__(256) void conv_all_kernel(const float* __restrict__ x,
                                                       const float* __restrict__ w_theta, const float* __restrict__ u_theta,
                                                       const float* __restrict__ w_phi,   const float* __restrict__ u_phi,
                                                       const float* __restrict__ w_g,     const float* __restrict__ u_g,
                                                       const float* __restrict__ w_o,     const float* __restrict__ u_o,
                                                       unsigned short* __restrict__ theta_bf,
                                                       unsigned short* __restrict__ phi_bf,
                                                       unsigned short* __restrict__ gT_bf,
                                                       unsigned short* __restrict__ woT_bf) {
    __shared__ unsigned short sx[128 * 72];  // x strip bf16, row pad 72 (reused for out-staging)
    __shared__ unsigned short sw[48 * 72];   // W^T [col][k], pad 72
    __shared__ float s_inv[3];

    const int tid  = threadIdx.x;
    const int b    = blockIdx.x >> 5;
    const int hp   = blockIdx.x & 31;        // rows 2hp, 2hp+1
    const int h0   = hp * 2;
    const int wv   = tid >> 6;
    const int lane = tid & 63;
    const int quad = lane >> 4;
    const int lcol = lane & 15;
    const int w0   = wv * 16;

    // stage x strip: 8192 floats = 2048 float4 -> 8 iters
    const float4* xb4 = (const float4*)(x + (((size_t)b * NPIX) + h0 * 64) * 64);
    #pragma unroll
    for (int it = 0; it < 8; ++it) {
        const int li = tid + it * 256;
        float4 v = xb4[li];
        const int px = li >> 4, c4 = li & 15;
        uint2 pk;
        pk.x = pack_bf16(v.x, v.y);
        pk.y = pack_bf16(v.z, v.w);
        *(uint2*)(&sx[px * 72 + c4 * 4]) = pk;
    }
    // per-wave spectral norm (redundant across blocks; weights are tiny + L2-hot)
    if (wv == 0)      { float iv = sn_inv_sigma<64, 8>(w_theta, u_theta); if (lane == 0) s_inv[0] = iv; }
    else if (wv == 1) { float iv = sn_inv_sigma<64, 8>(w_phi,   u_phi);   if (lane == 0) s_inv[1] = iv; }
    else if (wv == 2) { float iv = sn_inv_sigma<64, 32>(w_g,    u_g);     if (lane == 0) s_inv[2] = iv; }
    else if (blockIdx.x == 0) {
        // block 0 wave 3: w_o spectral norm -> woT_bf[n*32+k] = bf16(w_o[k][n]/sigma)
        float iv = sn_inv_sigma<32, 64>(w_o, u_o);
        for (int idx = lane; idx < 64 * 32; idx += 64) {
            const int n = idx >> 5, k = idx & 31;
            woT_bf[idx] = f2bf(w_o[k * 64 + n] * iv);
        }
    }
    __syncthreads();

    // fill sw: cols 0-7 theta, 8-15 phi, 16-47 g; sw[col][k] = bf16(w[k][col]/sigma)
    {
        const float i0 = s_inv[0], i1 = s_inv[1], i2 = s_inv[2];
        #pragma unroll
        for (int it = 0; it < 12; ++it) {
            const int idx = tid + it * 256;      // 0..3071; col is wave-uniform per iter
            const int col = idx >> 6, k = idx & 63;
            float wvf, inv;
            if (col < 8)       { wvf = w_theta[k * 8 + col];        inv = i0; }
            else if (col < 16) { wvf = w_phi[k * 8 + (col - 8)];    inv = i1; }
            else               { wvf = w_g[k * 32 + (col - 16)];    inv = i2; }
            sw[col * 72 + k] = f2bf(wvf * inv);
        }
    }
    __syncthreads();

    bf16x8 a[2][2];
    #pragma unroll
    for (int hh = 0; hh < 2; ++hh)
        #pragma unroll
        for (int kc = 0; kc < 2; ++kc)
            a[hh][kc] = *(const bf16x8*)(sx + (hh * 64 + w0 + lcol) * 72 + kc * 32 + quad * 8);

    f32x4 acc[2][3];
    #pragma unroll
    for (int ct = 0; ct < 3; ++ct) {
        bf16x8 b0 = *(const bf16x8*)(sw + (ct * 16 + lcol) * 72 + 0 * 32 + quad * 8);
        bf16x8 b1 = *(const bf16x8*)(sw + (ct * 16 + lcol) * 72 + 1 * 32 + quad * 8);
        #pragma unroll
        for (int hh = 0; hh < 2; ++hh) {
            f32x4 c = __builtin_amdgcn_mfma_f32_16x16x32_bf16(a[hh][0], b0, (f32x4)0.0f, 0, 0, 0);
            acc[hh][ct] = __builtin_amdgcn_mfma_f32_16x16x32_bf16(a[hh][1], b1, c, 0, 0, 0);
        }
    }
    __syncthreads();   // all LDS reads of sx/sw done -> safe to overlay staging tiles

    // ---- stage outputs in LDS (overlaid on sx), then write coalesced ----
    // th: 128px x 8ch = 1024 u16 @sx+0 ; ph: 32m x 8ch = 256 u16 @sx+1024 ;
    // gg: 32ch x 32m = 1024 u16 @sx+1280
    unsigned short* th = sx;
    unsigned short* ph = sx + 1024;
    unsigned short* gg = sx + 1280;
    const int ml = (w0 >> 1) + quad * 2;     // local pooled m within block, 0..31
    if (lcol < 8) {
        #pragma unroll
        for (int hh = 0; hh < 2; ++hh) {
            const int pix = hh * 64 + w0 + quad * 4;
            #pragma unroll
            for (int r = 0; r < 4; ++r)
                th[(pix + r) * 8 + lcol] = f2bf(acc[hh][0][r] * LOG2E);  // pre-scale for exp2
        }
    } else {
        #pragma unroll
        for (int r2 = 0; r2 < 2; ++r2) {
            float pe = fmaxf(fmaxf(acc[0][0][2 * r2], acc[0][0][2 * r2 + 1]),
                             fmaxf(acc[1][0][2 * r2], acc[1][0][2 * r2 + 1]));
            ph[(ml + r2) * 8 + (lcol - 8)] = f2bf(pe);
        }
    }
    #pragma unroll
    for (int ct = 1; ct < 3; ++ct) {
        const int cg = (ct - 1) * 16 + lcol;
        #pragma unroll
        for (int r2 = 0; r2 < 2; ++r2) {
            float pe = fmaxf(fmaxf(acc[0][ct][2 * r2], acc[0][ct][2 * r2 + 1]),
                             fmaxf(acc[1][ct][2 * r2], acc[1][ct][2 * r2 + 1]));
            gg[cg * 32 + ml + r2] = f2bf(pe);
        }
    }
    __syncthreads();

    // coalesced global writes: 288 float4 total (th 128, ph 32, gg 128)
    const float4* sv4 = (const float4*)sx;
    float4* th4 = (float4*)(theta_bf + ((size_t)b * NPIX + hp * 128) * 8);
    float4* ph4 = (float4*)(phi_bf + ((size_t)b * MPOOL + hp * 32) * 8);
    for (int idx = tid; idx < 288; idx += 256) {
        float4 v = sv4[idx];
        if (idx < 128) {
            th4[idx] = v;
        } else if (idx < 160) {
            ph4[idx - 128] = v;
        } else {
            const int gi = idx - 160;            // 0..127
            const int ch = gi >> 2, part = gi & 3;
            *(float4*)(gT_bf + ((size_t)b * 32 + ch) * MPOOL + hp * 32 + part * 8) = v;
        }
    }
}

// ---------------- fused MFMA attention + output conv + residual ----------------
// Block = 512 thr = 8 waves; wave = 16 q rows. Grid = 16 b x 32 qb.
// Single pass (no max subtraction: scores ~N(0,2), max ~11 << 88, fp32 exp safe).
// theta is PRE-SCALED by log2e -> softmax uses bare v_exp (exp2f).
// QK computed TRANSPOSED (A=phi, B=theta): lane's C-regs = 4 consecutive m's for
// fixed q=lcol -> cvt_pk_bf16 pair-packing, uint2 P stores, per-lane ls.
// Epilogue: out-conv with A=wo, B=ag -> D[ch][q], float4 residual stores;
// softmax 1/ls folded post-conv (per-q scaling commutes with channel conv).
__global__ __launch_bounds__(512) void attn_kernel(const unsigned short* __restrict__ theta_bf,
                                                   const unsigned short* __restrict__ phi_bf,
                                                   const unsigned short* __restrict__ gT_bf,
                                                   const unsigned short* __restrict__ woT_bf,
                                                   const float* __restrict__ x,
                                                   const float* __restrict__ gamma,
                                                   float* __restrict__ out) {
    __shared__ unsigned short sphi[MPOOL * 8];   // 16 KB
    __shared__ unsigned short sg[2][32 * 264];   // 33.8 KB: gT tile [32 ch][256 m + 8 pad]
    __shared__ unsigned short sP[8][16 * 72];    // 18.4 KB: per-wave P 16q x 64m, stride 72
    __shared__ unsigned short swo[64 * 40];      // 5.1 KB: woT [64 co][32 k + 8 pad]

    const int tid  = threadIdx.x;
    const int b    = blockIdx.x >> 5;
    const int qb   = blockIdx.x & 31;
    const int w    = tid >> 6;
    const int lane = tid & 63;
    const int quad = lane >> 4;
    const int lcol = lane & 15;

    // stage phi[b] (16 KB)
    {
        const float4* src = (const float4*)(phi_bf + (size_t)b * (MPOOL * 8));
        float4* dst = (float4*)sphi;
        dst[2 * tid]     = src[2 * tid];
        dst[2 * tid + 1] = src[2 * tid + 1];
    }
    // stage woT (precomputed by conv): 2048 u16 = 512 uint2, one per thread
    {
        const int n = tid >> 3, ks = (tid & 7) * 4;
        *(uint2*)(swo + n * 40 + ks) = *(const uint2*)(woT_bf + n * 32 + ks);
    }
    // stage gT tile 0
    const unsigned short* gTb = gT_bf + (size_t)b * (32 * MPOOL);
    const int prow = tid >> 4, pseg = tid & 15;
    {
        const float4* src = (const float4*)(gTb + prow * MPOOL + pseg * 16);
        float4 r0 = src[0], r1 = src[1];
        float4* dst = (float4*)(&sg[0][prow * 264 + pseg * 16]);
        dst[0] = r0; dst[1] = r1;
    }
    // theta frag (K=8 real, zero-pad k>=8 -> quads 1-3 zero); used as B operand.
    const int q0w = qb * 128 + w * 16;
    bf16x8 tfrag = (bf16x8)(short)0;
    if (quad == 0)
        tfrag = *(const bf16x8*)(theta_bf + ((size_t)b * NPIX + q0w + lcol) * 8);
    __syncthreads();

    f32x4 olo = (f32x4)0.0f, ohi = (f32x4)0.0f;
    float ls = 0.f;
    unsigned short* sPw = sP[w];

    float4 pre0, pre1;
    for (int t = 0; t < 4; ++t) {
        if (t < 3) {
            const float4* src = (const float4*)(gTb + prow * MPOOL + (t + 1) * 256 + pseg * 16);
            pre0 = src[0]; pre1 = src[1];
        }
        const unsigned short* sgb = sg[t & 1];
        for (int cb = 0; cb < 4; ++cb) {
            const int m0 = t * 256 + cb * 64;
            f32x4 s[4];
            #pragma unroll
            for (int sc = 0; sc < 4; ++sc) {
                bf16x8 pf = *(const bf16x8*)(sphi + (size_t)(m0 + sc * 16 + lcol) * 8);
                // S^T tile: D[row=m (quad*4+r within sc*16)][col=q (lcol)]
                s[sc] = __builtin_amdgcn_mfma_f32_16x16x32_bf16(pf, tfrag, (f32x4)0.0f, 0, 0, 0);
            }
            #pragma unroll
            for (int sc = 0; sc < 4; ++sc) {
                float e0 = exp2f(s[sc][0]);
                float e1 = exp2f(s[sc][1]);
                float e2 = exp2f(s[sc][2]);
                float e3 = exp2f(s[sc][3]);
                ls += (e0 + e1) + (e2 + e3);
                uint2 pk2;
                pk2.x = pack_bf16(e0, e1);
                pk2.y = pack_bf16(e2, e3);
                // P[q=lcol][m-in-chunk = sc*16 + quad*4 .. +3]
                *(uint2*)(sPw + lcol * 72 + sc * 16 + quad * 4) = pk2;
            }
            asm volatile("s_waitcnt lgkmcnt(0)" ::: "memory");
            #pragma unroll
            for (int pkk = 0; pkk < 2; ++pkk) {
                bf16x8 afrag = *(const bf16x8*)(sPw + lcol * 72 + pkk * 32 + quad * 8);
                bf16x8 bg0 = *(const bf16x8*)(sgb + lcol * 264 + cb * 64 + pkk * 32 + quad * 8);
                olo = __builtin_amdgcn_mfma_f32_16x16x32_bf16(afrag, bg0, olo, 0, 0, 0);
                bf16x8 bg1 = *(const bf16x8*)(sgb + (16 + lcol) * 264 + cb * 64 + pkk * 32 + quad * 8);
                ohi = __builtin_amdgcn_mfma_f32_16x16x32_bf16(afrag, bg1, ohi, 0, 0, 0);
            }
        }
        if (t < 3) {
            float4* dst = (float4*)(&sg[(t + 1) & 1][prow * 264 + pseg * 16]);
            dst[0] = pre0; dst[1] = pre1;
        }
        __syncthreads();
    }

    // total softmax denominator for q = lcol: sum over quads (lanes lcol+16k)
    ls += __shfl_xor(ls, 16);
    ls += __shfl_xor(ls, 32);
    const float invq = 1.0f / ls;

    // ag (UNNORMALIZED) -> per-wave LDS round-trip: [q][ch], stride 40
    #pragma unroll
    for (int r = 0; r < 4; ++r) {
        sPw[(quad * 4 + r) * 40 + lcol]      = f2bf(olo[r]);
        sPw[(quad * 4 + r) * 40 + 16 + lcol] = f2bf(ohi[r]);
    }
    asm volatile("s_waitcnt lgkmcnt(0)" ::: "memory");
    bf16x8 agf = *(const bf16x8*)(sPw + lcol * 40 + quad * 8);  // B[k=ch][n=q=lcol]

    const float gmi = gamma[0] * invq;
    const size_t pixbase = ((size_t)b * NPIX + q0w + lcol) * 64;
    #pragma unroll
    for (int ct = 0; ct < 4; ++ct) {
        bf16x8 wa = *(const bf16x8*)(swo + (ct * 16 + lcol) * 40 + quad * 8);  // A[co][k]
        f32x4 oc = __builtin_amdgcn_mfma_f32_16x16x32_bf16(wa, agf, (f32x4)0.0f, 0, 0, 0);
        // oc[r] = channel ct*16 + quad*4 + r at pixel q0w + lcol
        const float4 xv = *(const float4*)(x + pixbase + ct * 16 + quad * 4);
        float4 ov;
        ov.x = xv.x + gmi * oc[0];
        ov.y = xv.y + gmi * oc[1];
        ov.z = xv.z + gmi * oc[2];
        ov.w = xv.w + gmi * oc[3];
        *(float4*)(out + pixbase + ct * 16 + quad * 4) = ov;
    }
}

extern "C" void kernel_launch(void* const* d_in, const int* in_sizes, int n_in,
                              void* d_out, int out_size, void* d_ws, size_t ws_size,
                              hipStream_t stream) {
    const float* x       = (const float*)d_in[0];
    const float* w_theta = (const float*)d_in[1];
    const float* u_theta = (const float*)d_in[2];
    const float* w_phi   = (const float*)d_in[3];
    const float* u_phi   = (const float*)d_in[4];
    const float* w_g     = (const float*)d_in[5];
    const float* u_g     = (const float*)d_in[6];
    const float* w_o     = (const float*)d_in[7];
    const float* u_o     = (const float*)d_in[8];
    const float* gamma   = (const float*)d_in[9];
    float* out = (float*)d_out;

    unsigned short* u16base  = (unsigned short*)d_ws;
    unsigned short* theta_bf = u16base;                  // 524288
    unsigned short* phi_bf   = u16base + 524288;         // 131072
    unsigned short* gT_bf    = u16base + 655360;         // 524288
    unsigned short* woT_bf   = u16base + 1179648;        // 2048

    conv_all_kernel<<<512, 256, 0, stream>>>(x, w_theta, u_theta, w_phi, u_phi, w_g, u_g,
                                             w_o, u_o, theta_bf, phi_bf, gT_bf, woT_bf);
    attn_kernel<<<512, 512, 0, stream>>>(theta_bf, phi_bf, gT_bf, woT_bf, x, gamma, out);
}